// Round 15
// baseline (6339.726 us; speedup 1.0000x reference)
//
#include <hip/hip_runtime.h>
#include <math.h>

// KNRM-style ranker, fp32 end-to-end.
// R15 vs R14 (6.25ms): two incremental changes, rest verbatim R14.
//  - k_attn_doc: j-unroll x4 (one rescale/max per 4 keys, 4 batched exps,
//    8 independent dot chains, PV 32 indep vec FMAs). R14 was issue-bound:
//    ~6 serial scalars per key on top of 16 LDS + 16 FMA.
//  - k_score: 4 blocks/batch (8 queries each, grid 1024); fin sums 4 partials.

#define DMODEL 256
typedef float f32x4 __attribute__((ext_vector_type(4)));

// ---------------- positional-encoding table: pe[s][d], s<256 ----------------
__global__ __launch_bounds__(256) void k_pe(float* __restrict__ pe) {
  int s = blockIdx.x, d = threadIdx.x;
  int i2 = d & ~1;
  float freq = expf((float)i2 * (-9.210340371976184f / 256.f));
  float ang = (float)s * freq;
  pe[s * 256 + d] = (d & 1) ? cosf(ang) : sinf(ang);
}

// ---------------- embed (doc+query merged), 4 tokens / 256-thr block --------
__global__ __launch_bounds__(256) void k_embed(const int* __restrict__ dids,
    const int* __restrict__ qids, const float* __restrict__ emb,
    const float* __restrict__ pe, float* __restrict__ out_x) {
  int tid = threadIdx.x;
  int tok = blockIdx.x * 4 + (tid >> 6);
  int lane = tid & 63;
  int d0 = lane * 4;
  int id, s;
  if (tok < 65536) { id = dids[tok]; s = tok & 255; }
  else             { id = qids[tok - 65536]; s = (tok - 65536) & 31; }
  float m = id > 0 ? 2.f : 0.f;
  float4 e = *(const float4*)(emb + (size_t)id * DMODEL + d0);
  float4 p = *(const float4*)(pe + s * 256 + d0);
  float4 o;
  o.x = m * e.x + p.x; o.y = m * e.y + p.y;
  o.z = m * e.z + p.z; o.w = m * e.w + p.w;
  *(float4*)(out_x + (size_t)tok * DMODEL + d0) = o;
}

// ---------------- fp32 GEMM: out[M,N] = X[M,K] @ W[N,K(ldw)]^T (+bias|+=) ---
template<bool RELU, bool ACC>
__global__ __launch_bounds__(256) void k_gemm(const float* __restrict__ X,
    const float* __restrict__ W, const float* __restrict__ bias,
    float* __restrict__ out, int M, int N, int K, int ldw) {
  __shared__ float As[2][16][128];
  __shared__ float Bs[2][16][128];
  int n0 = blockIdx.x * 128;
  int m0 = blockIdx.y * 128;
  int tid = threadIdx.x;
  const int wv = tid >> 6, lane = tid & 63;
  const int r8 = lane >> 3, c8 = lane & 7;
  const int R0 = (wv & 1) * 64 + r8 * 4;
  const int C0 = (wv >> 1) * 64 + c8 * 4;
  int lr = tid >> 1;
  int lk = (tid & 1) << 3;
  const float* Xp = X + (size_t)(m0 + lr) * K + lk;
  const float* Wp = W + (size_t)(n0 + lr) * ldw + lk;

  float acc[8][8];
#pragma unroll
  for (int i = 0; i < 8; ++i)
#pragma unroll
    for (int j = 0; j < 8; ++j) acc[i][j] = 0.f;

  float4 a0, a1, b0, b1;

#define GLOADT(KT) do { \
    a0 = *(const float4*)(Xp + (KT)); a1 = *(const float4*)(Xp + (KT) + 4); \
    b0 = *(const float4*)(Wp + (KT)); b1 = *(const float4*)(Wp + (KT) + 4); } while (0)

#define LWRITE(BUF) do { \
    As[BUF][lk + 0][lr] = a0.x; As[BUF][lk + 1][lr] = a0.y; \
    As[BUF][lk + 2][lr] = a0.z; As[BUF][lk + 3][lr] = a0.w; \
    As[BUF][lk + 4][lr] = a1.x; As[BUF][lk + 5][lr] = a1.y; \
    As[BUF][lk + 6][lr] = a1.z; As[BUF][lk + 7][lr] = a1.w; \
    Bs[BUF][lk + 0][lr] = b0.x; Bs[BUF][lk + 1][lr] = b0.y; \
    Bs[BUF][lk + 2][lr] = b0.z; Bs[BUF][lk + 3][lr] = b0.w; \
    Bs[BUF][lk + 4][lr] = b1.x; Bs[BUF][lk + 5][lr] = b1.y; \
    Bs[BUF][lk + 6][lr] = b1.z; Bs[BUF][lk + 7][lr] = b1.w; } while (0)

#define COMPT(BUF) do { \
    _Pragma("unroll") \
    for (int k = 0; k < 16; ++k) { \
      float av[8], bv[8]; \
      *(float4*)&av[0] = *(const float4*)&As[BUF][k][R0]; \
      *(float4*)&av[4] = *(const float4*)&As[BUF][k][R0 + 32]; \
      *(float4*)&bv[0] = *(const float4*)&Bs[BUF][k][C0]; \
      *(float4*)&bv[4] = *(const float4*)&Bs[BUF][k][C0 + 32]; \
      _Pragma("unroll") \
      for (int i = 0; i < 8; ++i) \
        _Pragma("unroll") \
        for (int j = 0; j < 8; ++j) \
          acc[i][j] += av[i] * bv[j]; \
    } } while (0)

  const int nt = K >> 4;  // 8/16/32/128: even
  GLOADT(0);
  LWRITE(0);
  __syncthreads();
  for (int t = 0; t < nt; t += 2) {
    int k1 = (t + 1) * 16;
    GLOADT(k1);
    COMPT(0);
    LWRITE(1);
    __syncthreads();
    if (t + 2 < nt) {
      int k2 = (t + 2) * 16;
      GLOADT(k2);
      COMPT(1);
      LWRITE(0);
    } else {
      COMPT(1);
    }
    __syncthreads();
  }
#undef GLOADT
#undef LWRITE
#undef COMPT

#pragma unroll
  for (int i = 0; i < 8; ++i) {
    int mr = m0 + (wv & 1) * 64 + ((i < 4) ? (r8 * 4 + i) : (32 + r8 * 4 + i - 4));
#pragma unroll
    for (int jb = 0; jb < 2; ++jb) {
      int nc = n0 + (wv >> 1) * 64 + jb * 32 + c8 * 4;
      float4 o4;
      if (ACC) {
        float4 pv = *(const float4*)(out + (size_t)mr * N + nc);
        o4.x = acc[i][jb * 4 + 0] + pv.x;
        o4.y = acc[i][jb * 4 + 1] + pv.y;
        o4.z = acc[i][jb * 4 + 2] + pv.z;
        o4.w = acc[i][jb * 4 + 3] + pv.w;
      } else {
        float4 bz = *(const float4*)(bias + nc);
        o4.x = acc[i][jb * 4 + 0] + bz.x;
        o4.y = acc[i][jb * 4 + 1] + bz.y;
        o4.z = acc[i][jb * 4 + 2] + bz.z;
        o4.w = acc[i][jb * 4 + 3] + bz.w;
      }
      if (RELU) {
        o4.x = fmaxf(o4.x, 0.f); o4.y = fmaxf(o4.y, 0.f);
        o4.z = fmaxf(o4.z, 0.f); o4.w = fmaxf(o4.w, 0.f);
      }
      *(float4*)(out + (size_t)mr * N + nc) = o4;
    }
  }
}

// ---------------- GEMM (N=256) fused +residual+LayerNorm --------------------
template<bool ACCT0>
__global__ __launch_bounds__(256) void k_gemm_ln(const float* __restrict__ X,
    const float* __restrict__ W, const float* __restrict__ bias,
    float* __restrict__ xres, const float* __restrict__ tacc,
    const float* __restrict__ lns, const float* __restrict__ lnb,
    int M, int K, int ldw) {
  __shared__ float As[2][16][64];
  __shared__ float Bs[2][16][256];
  const int tid = threadIdx.x;
  const int m0 = blockIdx.x * 64;
  const int tx = tid & 15, ty = tid >> 4;
  const int rowA = tid & 63;
  const int kqA = (tid >> 6) << 2;
  const float* Xp = X + (size_t)(m0 + rowA) * K + kqA;
  const float* Wp = W + (size_t)tid * ldw;

  f32x4 acc[4][4];
#pragma unroll
  for (int r = 0; r < 4; ++r)
#pragma unroll
    for (int q = 0; q < 4; ++q) acc[r][q] = 0.f;

  f32x4 a, b0, b1, b2, b3;

#define GL(KT) do { \
    a  = *(const f32x4*)(Xp + (KT)); \
    b0 = *(const f32x4*)(Wp + (KT));      b1 = *(const f32x4*)(Wp + (KT) + 4); \
    b2 = *(const f32x4*)(Wp + (KT) + 8);  b3 = *(const f32x4*)(Wp + (KT) + 12); } while (0)

#define LW(BUF) do { \
    As[BUF][kqA + 0][rowA] = a[0]; As[BUF][kqA + 1][rowA] = a[1]; \
    As[BUF][kqA + 2][rowA] = a[2]; As[BUF][kqA + 3][rowA] = a[3]; \
    Bs[BUF][ 0][tid] = b0[0]; Bs[BUF][ 1][tid] = b0[1]; \
    Bs[BUF][ 2][tid] = b0[2]; Bs[BUF][ 3][tid] = b0[3]; \
    Bs[BUF][ 4][tid] = b1[0]; Bs[BUF][ 5][tid] = b1[1]; \
    Bs[BUF][ 6][tid] = b1[2]; Bs[BUF][ 7][tid] = b1[3]; \
    Bs[BUF][ 8][tid] = b2[0]; Bs[BUF][ 9][tid] = b2[1]; \
    Bs[BUF][10][tid] = b2[2]; Bs[BUF][11][tid] = b2[3]; \
    Bs[BUF][12][tid] = b3[0]; Bs[BUF][13][tid] = b3[1]; \
    Bs[BUF][14][tid] = b3[2]; Bs[BUF][15][tid] = b3[3]; } while (0)

#define CP(BUF) do { \
    _Pragma("unroll") \
    for (int k = 0; k < 16; ++k) { \
      f32x4 av = *(const f32x4*)&As[BUF][k][ty * 4]; \
      f32x4 bv0 = *(const f32x4*)&Bs[BUF][k][tx * 4]; \
      f32x4 bv1 = *(const f32x4*)&Bs[BUF][k][64 + tx * 4]; \
      f32x4 bv2 = *(const f32x4*)&Bs[BUF][k][128 + tx * 4]; \
      f32x4 bv3 = *(const f32x4*)&Bs[BUF][k][192 + tx * 4]; \
      _Pragma("unroll") \
      for (int r = 0; r < 4; ++r) { \
        acc[r][0] += av[r] * bv0; acc[r][1] += av[r] * bv1; \
        acc[r][2] += av[r] * bv2; acc[r][3] += av[r] * bv3; \
      } \
    } } while (0)

  const int nt = K >> 4;
  GL(0);
  LW(0);
  __syncthreads();
  for (int t = 0; t < nt; t += 2) {
    GL((t + 1) * 16);
    CP(0);
    LW(1);
    __syncthreads();
    if (t + 2 < nt) {
      GL((t + 2) * 16);
      CP(1);
      LW(0);
    } else {
      CP(1);
    }
    __syncthreads();
  }
#undef GL
#undef LW
#undef CP

  f32x4 bza[4], sca[4], lba[4];
#pragma unroll
  for (int q = 0; q < 4; ++q) {
    int c = q * 64 + tx * 4;
    if (!ACCT0) bza[q] = *(const f32x4*)(bias + c);
    sca[q] = *(const f32x4*)(lns + c);
    lba[q] = *(const f32x4*)(lnb + c);
  }
#pragma unroll
  for (int r = 0; r < 4; ++r) {
    size_t row = (size_t)m0 + ty * 4 + r;
    f32x4 v[4];
    float ps = 0.f;
#pragma unroll
    for (int q = 0; q < 4; ++q) {
      f32x4 xr = *(const f32x4*)(xres + row * 256 + q * 64 + tx * 4);
      f32x4 bs;
      if (ACCT0) bs = *(const f32x4*)(tacc + row * 256 + q * 64 + tx * 4);
      else       bs = bza[q];
      v[q] = acc[r][q] + bs + xr;
      ps += v[q][0] + v[q][1] + v[q][2] + v[q][3];
    }
    ps += __shfl_xor(ps, 1); ps += __shfl_xor(ps, 2);
    ps += __shfl_xor(ps, 4); ps += __shfl_xor(ps, 8);
    float mean = ps * (1.f / 256.f);
    float ss = 0.f;
#pragma unroll
    for (int q = 0; q < 4; ++q) {
      v[q] -= mean;
      ss += v[q][0] * v[q][0] + v[q][1] * v[q][1]
          + v[q][2] * v[q][2] + v[q][3] * v[q][3];
    }
    ss += __shfl_xor(ss, 1); ss += __shfl_xor(ss, 2);
    ss += __shfl_xor(ss, 4); ss += __shfl_xor(ss, 8);
    float rs = rsqrtf(ss * (1.f / 256.f) + 1e-5f);
#pragma unroll
    for (int q = 0; q < 4; ++q) {
      f32x4 y = v[q] * rs * sca[q] + lba[q];
      *(f32x4*)(xres + row * 256 + q * 64 + tx * 4) = y;
    }
  }
}

// ---------------- doc attention: 2 key-halves (32KB LDS), j-unroll x4 -------
__global__ __launch_bounds__(256) void k_attn_doc(const float* __restrict__ qkv,
    float* __restrict__ o, int b0) {
  __shared__ f32x4 Ks[128 * 8];
  __shared__ f32x4 Vs[128 * 8];
  int bl = blockIdx.x >> 3, h = blockIdx.x & 7;
  int tid = threadIdx.x;
  const float* base = qkv + (size_t)bl * 256 * 768;
  int hc = h * 32;
  f32x4 q[8], acc[8];
  const float* qp = base + (size_t)tid * 768 + hc;
#pragma unroll
  for (int w = 0; w < 8; ++w) { q[w] = *(const f32x4*)(qp + 4 * w); acc[w] = 0.f; }
  float m = -1e30f, l = 0.f;
  const float scale = 0.17677669529663687f;

  for (int half = 0; half < 2; ++half) {
    if (half) __syncthreads();
    for (int idx = tid; idx < 1024; idx += 256) {
      int s = idx >> 3, w = idx & 7;
      const float* kb = base + (size_t)(half * 128 + s) * 768;
      Ks[idx] = *(const f32x4*)(kb + 256 + hc + w * 4);
      Vs[idx] = *(const f32x4*)(kb + 512 + hc + w * 4);
    }
    __syncthreads();
    for (int j = 0; j < 128; j += 4) {
      const f32x4* kr0 = &Ks[(j + 0) * 8];
      const f32x4* kr1 = &Ks[(j + 1) * 8];
      const f32x4* kr2 = &Ks[(j + 2) * 8];
      const f32x4* kr3 = &Ks[(j + 3) * 8];
      f32x4 da0 = q[0] * kr0[0], db0 = q[1] * kr0[1];
      f32x4 da1 = q[0] * kr1[0], db1 = q[1] * kr1[1];
      f32x4 da2 = q[0] * kr2[0], db2 = q[1] * kr2[1];
      f32x4 da3 = q[0] * kr3[0], db3 = q[1] * kr3[1];
#pragma unroll
      for (int w = 2; w < 8; w += 2) {
        da0 += q[w] * kr0[w];  db0 += q[w + 1] * kr0[w + 1];
        da1 += q[w] * kr1[w];  db1 += q[w + 1] * kr1[w + 1];
        da2 += q[w] * kr2[w];  db2 += q[w + 1] * kr2[w + 1];
        da3 += q[w] * kr3[w];  db3 += q[w + 1] * kr3[w + 1];
      }
      f32x4 d40 = da0 + db0, d41 = da1 + db1;
      f32x4 d42 = da2 + db2, d43 = da3 + db3;
      float s0 = (d40[0] + d40[1] + d40[2] + d40[3]) * scale;
      float s1 = (d41[0] + d41[1] + d41[2] + d41[3]) * scale;
      float s2 = (d42[0] + d42[1] + d42[2] + d42[3]) * scale;
      float s3 = (d43[0] + d43[1] + d43[2] + d43[3]) * scale;
      float mx = fmaxf(fmaxf(s0, s1), fmaxf(s2, s3));
      float mn = fmaxf(m, mx);
      float p0 = __expf(s0 - mn);
      float p1 = __expf(s1 - mn);
      float p2 = __expf(s2 - mn);
      float p3 = __expf(s3 - mn);
      if (mn > m) {
        float al = __expf(m - mn);
        l *= al;
#pragma unroll
        for (int w = 0; w < 8; ++w) acc[w] *= al;
        m = mn;
      }
      l += (p0 + p1) + (p2 + p3);
      const f32x4* vr0 = &Vs[(j + 0) * 8];
      const f32x4* vr1 = &Vs[(j + 1) * 8];
      const f32x4* vr2 = &Vs[(j + 2) * 8];
      const f32x4* vr3 = &Vs[(j + 3) * 8];
#pragma unroll
      for (int w = 0; w < 8; ++w)
        acc[w] += (p0 * vr0[w] + p1 * vr1[w]) + (p2 * vr2[w] + p3 * vr3[w]);
    }
  }
  float inv = 1.f / l;
  float* op = o + ((size_t)(b0 + bl) * 256 + tid) * DMODEL + hc;
#pragma unroll
  for (int w = 0; w < 8; ++w) *(f32x4*)(op + 4 * w) = acc[w] * inv;
}

// ---------------- query attention: block=batch, 256 thr=(head,row) ----------
__global__ __launch_bounds__(256) void k_attn_qry(const float* __restrict__ qkv,
    float* __restrict__ o) {
  __shared__ f32x4 Ks[32 * 64];
  __shared__ f32x4 Vs[32 * 64];
  int bl = blockIdx.x;
  int tid = threadIdx.x;
  const float* base = qkv + (size_t)bl * 32 * 768;
  for (int idx = tid; idx < 2048; idx += 256) {
    int s = idx >> 6, c = idx & 63;
    Ks[idx] = *(const f32x4*)(base + (size_t)s * 768 + 256 + c * 4);
    Vs[idx] = *(const f32x4*)(base + (size_t)s * 768 + 512 + c * 4);
  }
  __syncthreads();
  int h = tid >> 5, row = tid & 31;
  int hc = h * 32;
  f32x4 q[8], acc[8];
  const float* qp = base + (size_t)row * 768 + hc;
#pragma unroll
  for (int w = 0; w < 8; ++w) { q[w] = *(const f32x4*)(qp + 4 * w); acc[w] = 0.f; }
  float m = -1e30f, l = 0.f;
  const float scale = 0.17677669529663687f;
  for (int j = 0; j < 32; ++j) {
    const f32x4* kr = &Ks[j * 64 + h * 8];
    f32x4 da = q[0] * kr[0];
    f32x4 db = q[1] * kr[1];
#pragma unroll
    for (int w = 2; w < 8; w += 2) {
      da += q[w] * kr[w];
      db += q[w + 1] * kr[w + 1];
    }
    f32x4 d4 = da + db;
    float s_ = (d4[0] + d4[1] + d4[2] + d4[3]) * scale;
    float mn = fmaxf(m, s_);
    float p = __expf(s_ - mn);
    if (mn > m) {
      float al = __expf(m - mn);
      l *= al;
#pragma unroll
      for (int w = 0; w < 8; ++w) acc[w] *= al;
      m = mn;
    }
    l += p;
    const f32x4* vr = &Vs[j * 64 + h * 8];
#pragma unroll
    for (int w = 0; w < 8; ++w) acc[w] += p * vr[w];
  }
  float inv = 1.f / l;
  float* op = o + ((size_t)bl * 32 + row) * DMODEL + hc;
#pragma unroll
  for (int w = 0; w < 8; ++w) *(f32x4*)(op + 4 * w) = acc[w] * inv;
}

// ---------------- scoring stage 1: block=(batch, query-quarter) -------------
// 8 queries per block, grid 1024 (4 blocks/CU). Per-wave qks slots, no
// atomics; partial score -> part[blk].
__global__ __launch_bounds__(256) void k_score(
    const int* __restrict__ qids, const int* __restrict__ dids,
    const float* __restrict__ emb, const float* __restrict__ xq,
    const float* __restrict__ xd, const float* __restrict__ a_ptr,
    const float* __restrict__ mlp_w, float* __restrict__ part) {
  __shared__ float qmix[8 * 256];
  __shared__ float qks[4][8][11];
  __shared__ float qmask_s[8];
  __shared__ float mw_s[11];
  int blk = blockIdx.x;
  int b = blk >> 2, quar = blk & 3;
  int tid = threadIdx.x;
  int wv = tid >> 6, lane = tid & 63;
  float av = a_ptr[0], aw = 1.f - av;
  for (int q = 0; q < 8; ++q) {
    int qg = quar * 8 + q;
    int qid = qids[b * 32 + qg];
    float qm = qid > 0 ? 1.f : 0.f;
    float ev = emb[(size_t)qid * 256 + tid];
    float xv = xq[((size_t)b * 32 + qg) * 256 + tid];
    qmix[q * 256 + tid] = (av * ev + aw * xv) * qm;
    if (tid == 0) qmask_s[q] = qm;
  }
  if (tid < 11) mw_s[tid] = mlp_w[tid];
  __syncthreads();
  int j = tid;
  int did = dids[b * 256 + j];
  float dmask = did > 0 ? 1.f : 0.f;
  float sim[8];
#pragma unroll
  for (int q = 0; q < 8; ++q) sim[q] = 0.f;
  const float4* de = (const float4*)(emb + (size_t)did * 256);
  const float4* dxp = (const float4*)(xd + ((size_t)b * 256 + j) * 256);
  for (int c = 0; c < 4; ++c) {
    float4 dreg[16];
#pragma unroll
    for (int w = 0; w < 16; ++w) {
      float4 e = de[c * 16 + w], x = dxp[c * 16 + w];
      dreg[w].x = av * e.x + aw * x.x;
      dreg[w].y = av * e.y + aw * x.y;
      dreg[w].z = av * e.z + aw * x.z;
      dreg[w].w = av * e.w + aw * x.w;
    }
#pragma unroll
    for (int q = 0; q < 8; ++q) {
      const float4* qp = (const float4*)&qmix[q * 256 + c * 64];
      float d_ = 0.f;
#pragma unroll
      for (int w = 0; w < 16; ++w) {
        float4 t = qp[w];
        d_ += t.x * dreg[w].x + t.y * dreg[w].y + t.z * dreg[w].z + t.w * dreg[w].w;
      }
      sim[q] += d_;
    }
  }
  const float MU[11] = {1.f, 0.9f, 0.7f, 0.5f, 0.3f, 0.1f, -0.1f, -0.3f, -0.5f, -0.7f, -0.9f};
  const float IC[11] = {5e7f, 50.f, 50.f, 50.f, 50.f, 50.f, 50.f, 50.f, 50.f, 50.f, 50.f};
  for (int q = 0; q < 8; ++q) {
    float s = sim[q];
    float f = dmask * qmask_s[q];
#pragma unroll
    for (int k = 0; k < 11; ++k) {
      float d_ = s - MU[k];
      float v = expf(-d_ * d_ * IC[k]) * f;
#pragma unroll
      for (int o = 32; o > 0; o >>= 1) v += __shfl_xor(v, o);
      if (lane == 0) qks[wv][q][k] = v;
    }
  }
  __syncthreads();
  if (tid < 88) {
    int q = tid / 11, k = tid - q * 11;
    float kv = (qks[0][q][k] + qks[1][q][k]) + (qks[2][q][k] + qks[3][q][k]);
    qks[0][q][k] = mw_s[k] * (qmask_s[q] * logf(fmaxf(kv, 1e-10f))
                              + kv * (1.f / 256.f));
  }
  __syncthreads();
  if (tid < 8) {
    float p = 0.f;
#pragma unroll
    for (int k = 0; k < 11; ++k) p += qks[0][tid][k];
#pragma unroll
    for (int o = 4; o > 0; o >>= 1) p += __shfl_xor(p, o);
    if (tid == 0) part[blk] = p;
  }
}

// ---------------- scoring stage 2: combine quarter partials -----------------
__global__ __launch_bounds__(256) void k_score_fin(const float* __restrict__ part,
    float* __restrict__ out) {
  int b = threadIdx.x;
  out[b] = (part[4 * b] + part[4 * b + 1]) + (part[4 * b + 2] + part[4 * b + 3]);
}

extern "C" void kernel_launch(void* const* d_in, const int* in_sizes, int n_in,
                              void* d_out, int out_size, void* d_ws, size_t ws_size,
                              hipStream_t stream) {
  const int* qids = (const int*)d_in[0];
  const int* dids = (const int*)d_in[1];
  const float* emb = (const float*)d_in[2];
  const float* a = (const float*)d_in[3];
  const float* mlp_w = (const float*)d_in[4];
  const float* Wqkv = (const float*)d_in[5];
  const float* bqkv = (const float*)d_in[6];
  const float* Wo = (const float*)d_in[7];
  const float* bo = (const float*)d_in[8];
  const float* l1s = (const float*)d_in[9];
  const float* l1b = (const float*)d_in[10];
  const float* W1 = (const float*)d_in[11];
  const float* b1 = (const float*)d_in[12];
  const float* W2 = (const float*)d_in[13];
  const float* b2 = (const float*)d_in[14];
  const float* l2s = (const float*)d_in[15];
  const float* l2b = (const float*)d_in[16];
  float* out = (float*)d_out;
  float* ws = (float*)d_ws;

  const int TOK = 73728;                      // 65536 doc + 8192 query tokens
  size_t wsf = ws_size / 4;
  const size_t fixed = 2 * (size_t)TOK * 256 + 65536;  // x + t0 + pe

  int FW = 128, CB = 32;
  bool merged = false;
  if (fixed + (size_t)40960 * 768 <= wsf) {
    merged = true; FW = 256; CB = 128;                                     // 277MB
  } else if (fixed + (size_t)128 * 196608 <= wsf) {
    FW = 256; CB = 128;                                                    // 252MB
  } else if (fixed + (size_t)TOK * 256 <= wsf) {
    FW = 256; CB = 64;                                                     // 227MB
  } else {
    FW = 128; CB = 32;                                                     // 189MB
  }

  float* x       = ws;
  float* t0      = x + (size_t)TOK * 256;
  float* pe      = t0 + (size_t)TOK * 256;
  float* scratch = pe + 65536;   // qkv chunk | h_part | score partials

  k_pe<<<256, 256, 0, stream>>>(pe);
  k_embed<<<TOK / 4, 256, 0, stream>>>(dids, qids, emb, pe, x);

  for (int l = 0; l < 2; ++l) {
    const float* wq = Wqkv + (size_t)l * 768 * 256;
    const float* bq = bqkv + l * 768;
    const float* wo = Wo + (size_t)l * 256 * 256;
    const float* bo_ = bo + l * 256;
    const float* w1 = W1 + (size_t)l * 2048 * 256;
    const float* b1_ = b1 + l * 2048;
    const float* w2 = W2 + (size_t)l * 256 * 2048;
    const float* b2_ = b2 + l * 256;

    if (merged) {
      k_gemm<false, false><<<dim3(6, 256), 256, 0, stream>>>(
          x, wq, bq, scratch, 32768, 768, 256, 256);
      k_attn_doc<<<1024, 256, 0, stream>>>(scratch, t0, 0);
      k_gemm<false, false><<<dim3(6, 320), 256, 0, stream>>>(
          x + (size_t)32768 * 256, wq, bq, scratch, 40960, 768, 256, 256);
      k_attn_doc<<<1024, 256, 0, stream>>>(scratch, t0, 128);
      k_attn_qry<<<256, 256, 0, stream>>>(scratch + (size_t)32768 * 768,
                                          t0 + (size_t)65536 * 256);
    } else {
      for (int c = 0; c < 256; c += CB) {
        int Mc = CB * 256;
        k_gemm<false, false><<<dim3(6, Mc / 128), 256, 0, stream>>>(
            x + (size_t)c * 65536, wq, bq, scratch, Mc, 768, 256, 256);
        k_attn_doc<<<CB * 8, 256, 0, stream>>>(scratch, t0, c);
      }
      k_gemm<false, false><<<dim3(6, 64), 256, 0, stream>>>(
          x + (size_t)65536 * 256, wq, bq, scratch, 8192, 768, 256, 256);
      k_attn_qry<<<256, 256, 0, stream>>>(scratch, t0 + (size_t)65536 * 256);
    }
    // Wo + bias + residual + LN1, in-place into x
    k_gemm_ln<false><<<TOK / 64, 256, 0, stream>>>(t0, wo, bo_, x, t0,
        l1s + l * 256, l1b + l * 256, TOK, 256, 256);
    // FFN, ff-sliced (FW); last W2 slice fused with residual+LN2
    int nparts = 2048 / FW;
    for (int p = 0; p < nparts; ++p) {
      k_gemm<true, false><<<dim3(FW / 128, TOK / 128), 256, 0, stream>>>(
          x, w1 + (size_t)p * FW * 256, b1_ + p * FW, scratch, TOK, FW, 256, 256);
      if (p == 0)
        k_gemm<false, false><<<dim3(2, TOK / 128), 256, 0, stream>>>(
            scratch, w2, b2_, t0, TOK, 256, FW, 2048);
      else if (p < nparts - 1)
        k_gemm<false, true><<<dim3(2, TOK / 128), 256, 0, stream>>>(
            scratch, w2 + (size_t)p * FW, b2_, t0, TOK, 256, FW, 2048);
      else
        k_gemm_ln<true><<<TOK / 64, 256, 0, stream>>>(
            scratch, w2 + (size_t)p * FW, b2_, x, t0,
            l2s + l * 256, l2b + l * 256, TOK, FW, 2048);
    }
  }

  // scoring: 4 blocks per batch -> partials -> combine
  float* part = scratch;
  k_score<<<1024, 256, 0, stream>>>(qids, dids, emb, x + (size_t)65536 * 256,
                                    x, a, mlp_w, part);
  k_score_fin<<<1, 256, 0, stream>>>(part, out);
}

// Round 16
// 6247.169 us; speedup vs baseline: 1.0148x; 1.0148x over previous
//
#include <hip/hip_runtime.h>
#include <math.h>

// KNRM-style ranker, fp32 end-to-end.
// R16 = R15 with k_score reverted to the R12 2-block/batch version.
// R15's 4-block query-split quadrupled doc re-reads (FETCH 73MB->469MB,
// BW-bound 208us); 2-block redundancy is L3-absorbable (<=166us, R12).
// Kept from R15: attn_doc j-unroll x4 + 32KB LDS halves; FW=256 ff-slices;
// merged QKV; fused Wo/W2 LN epilogues.

#define DMODEL 256
typedef float f32x4 __attribute__((ext_vector_type(4)));

// ---------------- positional-encoding table: pe[s][d], s<256 ----------------
__global__ __launch_bounds__(256) void k_pe(float* __restrict__ pe) {
  int s = blockIdx.x, d = threadIdx.x;
  int i2 = d & ~1;
  float freq = expf((float)i2 * (-9.210340371976184f / 256.f));
  float ang = (float)s * freq;
  pe[s * 256 + d] = (d & 1) ? cosf(ang) : sinf(ang);
}

// ---------------- embed (doc+query merged), 4 tokens / 256-thr block --------
__global__ __launch_bounds__(256) void k_embed(const int* __restrict__ dids,
    const int* __restrict__ qids, const float* __restrict__ emb,
    const float* __restrict__ pe, float* __restrict__ out_x) {
  int tid = threadIdx.x;
  int tok = blockIdx.x * 4 + (tid >> 6);
  int lane = tid & 63;
  int d0 = lane * 4;
  int id, s;
  if (tok < 65536) { id = dids[tok]; s = tok & 255; }
  else             { id = qids[tok - 65536]; s = (tok - 65536) & 31; }
  float m = id > 0 ? 2.f : 0.f;
  float4 e = *(const float4*)(emb + (size_t)id * DMODEL + d0);
  float4 p = *(const float4*)(pe + s * 256 + d0);
  float4 o;
  o.x = m * e.x + p.x; o.y = m * e.y + p.y;
  o.z = m * e.z + p.z; o.w = m * e.w + p.w;
  *(float4*)(out_x + (size_t)tok * DMODEL + d0) = o;
}

// ---------------- fp32 GEMM: out[M,N] = X[M,K] @ W[N,K(ldw)]^T (+bias|+=) ---
template<bool RELU, bool ACC>
__global__ __launch_bounds__(256) void k_gemm(const float* __restrict__ X,
    const float* __restrict__ W, const float* __restrict__ bias,
    float* __restrict__ out, int M, int N, int K, int ldw) {
  __shared__ float As[2][16][128];
  __shared__ float Bs[2][16][128];
  int n0 = blockIdx.x * 128;
  int m0 = blockIdx.y * 128;
  int tid = threadIdx.x;
  const int wv = tid >> 6, lane = tid & 63;
  const int r8 = lane >> 3, c8 = lane & 7;
  const int R0 = (wv & 1) * 64 + r8 * 4;
  const int C0 = (wv >> 1) * 64 + c8 * 4;
  int lr = tid >> 1;
  int lk = (tid & 1) << 3;
  const float* Xp = X + (size_t)(m0 + lr) * K + lk;
  const float* Wp = W + (size_t)(n0 + lr) * ldw + lk;

  float acc[8][8];
#pragma unroll
  for (int i = 0; i < 8; ++i)
#pragma unroll
    for (int j = 0; j < 8; ++j) acc[i][j] = 0.f;

  float4 a0, a1, b0, b1;

#define GLOADT(KT) do { \
    a0 = *(const float4*)(Xp + (KT)); a1 = *(const float4*)(Xp + (KT) + 4); \
    b0 = *(const float4*)(Wp + (KT)); b1 = *(const float4*)(Wp + (KT) + 4); } while (0)

#define LWRITE(BUF) do { \
    As[BUF][lk + 0][lr] = a0.x; As[BUF][lk + 1][lr] = a0.y; \
    As[BUF][lk + 2][lr] = a0.z; As[BUF][lk + 3][lr] = a0.w; \
    As[BUF][lk + 4][lr] = a1.x; As[BUF][lk + 5][lr] = a1.y; \
    As[BUF][lk + 6][lr] = a1.z; As[BUF][lk + 7][lr] = a1.w; \
    Bs[BUF][lk + 0][lr] = b0.x; Bs[BUF][lk + 1][lr] = b0.y; \
    Bs[BUF][lk + 2][lr] = b0.z; Bs[BUF][lk + 3][lr] = b0.w; \
    Bs[BUF][lk + 4][lr] = b1.x; Bs[BUF][lk + 5][lr] = b1.y; \
    Bs[BUF][lk + 6][lr] = b1.z; Bs[BUF][lk + 7][lr] = b1.w; } while (0)

#define COMPT(BUF) do { \
    _Pragma("unroll") \
    for (int k = 0; k < 16; ++k) { \
      float av[8], bv[8]; \
      *(float4*)&av[0] = *(const float4*)&As[BUF][k][R0]; \
      *(float4*)&av[4] = *(const float4*)&As[BUF][k][R0 + 32]; \
      *(float4*)&bv[0] = *(const float4*)&Bs[BUF][k][C0]; \
      *(float4*)&bv[4] = *(const float4*)&Bs[BUF][k][C0 + 32]; \
      _Pragma("unroll") \
      for (int i = 0; i < 8; ++i) \
        _Pragma("unroll") \
        for (int j = 0; j < 8; ++j) \
          acc[i][j] += av[i] * bv[j]; \
    } } while (0)

  const int nt = K >> 4;  // 8/16/32/128: even
  GLOADT(0);
  LWRITE(0);
  __syncthreads();
  for (int t = 0; t < nt; t += 2) {
    int k1 = (t + 1) * 16;
    GLOADT(k1);
    COMPT(0);
    LWRITE(1);
    __syncthreads();
    if (t + 2 < nt) {
      int k2 = (t + 2) * 16;
      GLOADT(k2);
      COMPT(1);
      LWRITE(0);
    } else {
      COMPT(1);
    }
    __syncthreads();
  }
#undef GLOADT
#undef LWRITE
#undef COMPT

#pragma unroll
  for (int i = 0; i < 8; ++i) {
    int mr = m0 + (wv & 1) * 64 + ((i < 4) ? (r8 * 4 + i) : (32 + r8 * 4 + i - 4));
#pragma unroll
    for (int jb = 0; jb < 2; ++jb) {
      int nc = n0 + (wv >> 1) * 64 + jb * 32 + c8 * 4;
      float4 o4;
      if (ACC) {
        float4 pv = *(const float4*)(out + (size_t)mr * N + nc);
        o4.x = acc[i][jb * 4 + 0] + pv.x;
        o4.y = acc[i][jb * 4 + 1] + pv.y;
        o4.z = acc[i][jb * 4 + 2] + pv.z;
        o4.w = acc[i][jb * 4 + 3] + pv.w;
      } else {
        float4 bz = *(const float4*)(bias + nc);
        o4.x = acc[i][jb * 4 + 0] + bz.x;
        o4.y = acc[i][jb * 4 + 1] + bz.y;
        o4.z = acc[i][jb * 4 + 2] + bz.z;
        o4.w = acc[i][jb * 4 + 3] + bz.w;
      }
      if (RELU) {
        o4.x = fmaxf(o4.x, 0.f); o4.y = fmaxf(o4.y, 0.f);
        o4.z = fmaxf(o4.z, 0.f); o4.w = fmaxf(o4.w, 0.f);
      }
      *(float4*)(out + (size_t)mr * N + nc) = o4;
    }
  }
}

// ---------------- GEMM (N=256) fused +residual+LayerNorm --------------------
template<bool ACCT0>
__global__ __launch_bounds__(256) void k_gemm_ln(const float* __restrict__ X,
    const float* __restrict__ W, const float* __restrict__ bias,
    float* __restrict__ xres, const float* __restrict__ tacc,
    const float* __restrict__ lns, const float* __restrict__ lnb,
    int M, int K, int ldw) {
  __shared__ float As[2][16][64];
  __shared__ float Bs[2][16][256];
  const int tid = threadIdx.x;
  const int m0 = blockIdx.x * 64;
  const int tx = tid & 15, ty = tid >> 4;
  const int rowA = tid & 63;
  const int kqA = (tid >> 6) << 2;
  const float* Xp = X + (size_t)(m0 + rowA) * K + kqA;
  const float* Wp = W + (size_t)tid * ldw;

  f32x4 acc[4][4];
#pragma unroll
  for (int r = 0; r < 4; ++r)
#pragma unroll
    for (int q = 0; q < 4; ++q) acc[r][q] = 0.f;

  f32x4 a, b0, b1, b2, b3;

#define GL(KT) do { \
    a  = *(const f32x4*)(Xp + (KT)); \
    b0 = *(const f32x4*)(Wp + (KT));      b1 = *(const f32x4*)(Wp + (KT) + 4); \
    b2 = *(const f32x4*)(Wp + (KT) + 8);  b3 = *(const f32x4*)(Wp + (KT) + 12); } while (0)

#define LW(BUF) do { \
    As[BUF][kqA + 0][rowA] = a[0]; As[BUF][kqA + 1][rowA] = a[1]; \
    As[BUF][kqA + 2][rowA] = a[2]; As[BUF][kqA + 3][rowA] = a[3]; \
    Bs[BUF][ 0][tid] = b0[0]; Bs[BUF][ 1][tid] = b0[1]; \
    Bs[BUF][ 2][tid] = b0[2]; Bs[BUF][ 3][tid] = b0[3]; \
    Bs[BUF][ 4][tid] = b1[0]; Bs[BUF][ 5][tid] = b1[1]; \
    Bs[BUF][ 6][tid] = b1[2]; Bs[BUF][ 7][tid] = b1[3]; \
    Bs[BUF][ 8][tid] = b2[0]; Bs[BUF][ 9][tid] = b2[1]; \
    Bs[BUF][10][tid] = b2[2]; Bs[BUF][11][tid] = b2[3]; \
    Bs[BUF][12][tid] = b3[0]; Bs[BUF][13][tid] = b3[1]; \
    Bs[BUF][14][tid] = b3[2]; Bs[BUF][15][tid] = b3[3]; } while (0)

#define CP(BUF) do { \
    _Pragma("unroll") \
    for (int k = 0; k < 16; ++k) { \
      f32x4 av = *(const f32x4*)&As[BUF][k][ty * 4]; \
      f32x4 bv0 = *(const f32x4*)&Bs[BUF][k][tx * 4]; \
      f32x4 bv1 = *(const f32x4*)&Bs[BUF][k][64 + tx * 4]; \
      f32x4 bv2 = *(const f32x4*)&Bs[BUF][k][128 + tx * 4]; \
      f32x4 bv3 = *(const f32x4*)&Bs[BUF][k][192 + tx * 4]; \
      _Pragma("unroll") \
      for (int r = 0; r < 4; ++r) { \
        acc[r][0] += av[r] * bv0; acc[r][1] += av[r] * bv1; \
        acc[r][2] += av[r] * bv2; acc[r][3] += av[r] * bv3; \
      } \
    } } while (0)

  const int nt = K >> 4;
  GL(0);
  LW(0);
  __syncthreads();
  for (int t = 0; t < nt; t += 2) {
    GL((t + 1) * 16);
    CP(0);
    LW(1);
    __syncthreads();
    if (t + 2 < nt) {
      GL((t + 2) * 16);
      CP(1);
      LW(0);
    } else {
      CP(1);
    }
    __syncthreads();
  }
#undef GL
#undef LW
#undef CP

  f32x4 bza[4], sca[4], lba[4];
#pragma unroll
  for (int q = 0; q < 4; ++q) {
    int c = q * 64 + tx * 4;
    if (!ACCT0) bza[q] = *(const f32x4*)(bias + c);
    sca[q] = *(const f32x4*)(lns + c);
    lba[q] = *(const f32x4*)(lnb + c);
  }
#pragma unroll
  for (int r = 0; r < 4; ++r) {
    size_t row = (size_t)m0 + ty * 4 + r;
    f32x4 v[4];
    float ps = 0.f;
#pragma unroll
    for (int q = 0; q < 4; ++q) {
      f32x4 xr = *(const f32x4*)(xres + row * 256 + q * 64 + tx * 4);
      f32x4 bs;
      if (ACCT0) bs = *(const f32x4*)(tacc + row * 256 + q * 64 + tx * 4);
      else       bs = bza[q];
      v[q] = acc[r][q] + bs + xr;
      ps += v[q][0] + v[q][1] + v[q][2] + v[q][3];
    }
    ps += __shfl_xor(ps, 1); ps += __shfl_xor(ps, 2);
    ps += __shfl_xor(ps, 4); ps += __shfl_xor(ps, 8);
    float mean = ps * (1.f / 256.f);
    float ss = 0.f;
#pragma unroll
    for (int q = 0; q < 4; ++q) {
      v[q] -= mean;
      ss += v[q][0] * v[q][0] + v[q][1] * v[q][1]
          + v[q][2] * v[q][2] + v[q][3] * v[q][3];
    }
    ss += __shfl_xor(ss, 1); ss += __shfl_xor(ss, 2);
    ss += __shfl_xor(ss, 4); ss += __shfl_xor(ss, 8);
    float rs = rsqrtf(ss * (1.f / 256.f) + 1e-5f);
#pragma unroll
    for (int q = 0; q < 4; ++q) {
      f32x4 y = v[q] * rs * sca[q] + lba[q];
      *(f32x4*)(xres + row * 256 + q * 64 + tx * 4) = y;
    }
  }
}

// ---------------- doc attention: 2 key-halves (32KB LDS), j-unroll x4 -------
__global__ __launch_bounds__(256) void k_attn_doc(const float* __restrict__ qkv,
    float* __restrict__ o, int b0) {
  __shared__ f32x4 Ks[128 * 8];
  __shared__ f32x4 Vs[128 * 8];
  int bl = blockIdx.x >> 3, h = blockIdx.x & 7;
  int tid = threadIdx.x;
  const float* base = qkv + (size_t)bl * 256 * 768;
  int hc = h * 32;
  f32x4 q[8], acc[8];
  const float* qp = base + (size_t)tid * 768 + hc;
#pragma unroll
  for (int w = 0; w < 8; ++w) { q[w] = *(const f32x4*)(qp + 4 * w); acc[w] = 0.f; }
  float m = -1e30f, l = 0.f;
  const float scale = 0.17677669529663687f;

  for (int half = 0; half < 2; ++half) {
    if (half) __syncthreads();
    for (int idx = tid; idx < 1024; idx += 256) {
      int s = idx >> 3, w = idx & 7;
      const float* kb = base + (size_t)(half * 128 + s) * 768;
      Ks[idx] = *(const f32x4*)(kb + 256 + hc + w * 4);
      Vs[idx] = *(const f32x4*)(kb + 512 + hc + w * 4);
    }
    __syncthreads();
    for (int j = 0; j < 128; j += 4) {
      const f32x4* kr0 = &Ks[(j + 0) * 8];
      const f32x4* kr1 = &Ks[(j + 1) * 8];
      const f32x4* kr2 = &Ks[(j + 2) * 8];
      const f32x4* kr3 = &Ks[(j + 3) * 8];
      f32x4 da0 = q[0] * kr0[0], db0 = q[1] * kr0[1];
      f32x4 da1 = q[0] * kr1[0], db1 = q[1] * kr1[1];
      f32x4 da2 = q[0] * kr2[0], db2 = q[1] * kr2[1];
      f32x4 da3 = q[0] * kr3[0], db3 = q[1] * kr3[1];
#pragma unroll
      for (int w = 2; w < 8; w += 2) {
        da0 += q[w] * kr0[w];  db0 += q[w + 1] * kr0[w + 1];
        da1 += q[w] * kr1[w];  db1 += q[w + 1] * kr1[w + 1];
        da2 += q[w] * kr2[w];  db2 += q[w + 1] * kr2[w + 1];
        da3 += q[w] * kr3[w];  db3 += q[w + 1] * kr3[w + 1];
      }
      f32x4 d40 = da0 + db0, d41 = da1 + db1;
      f32x4 d42 = da2 + db2, d43 = da3 + db3;
      float s0 = (d40[0] + d40[1] + d40[2] + d40[3]) * scale;
      float s1 = (d41[0] + d41[1] + d41[2] + d41[3]) * scale;
      float s2 = (d42[0] + d42[1] + d42[2] + d42[3]) * scale;
      float s3 = (d43[0] + d43[1] + d43[2] + d43[3]) * scale;
      float mx = fmaxf(fmaxf(s0, s1), fmaxf(s2, s3));
      float mn = fmaxf(m, mx);
      float p0 = __expf(s0 - mn);
      float p1 = __expf(s1 - mn);
      float p2 = __expf(s2 - mn);
      float p3 = __expf(s3 - mn);
      if (mn > m) {
        float al = __expf(m - mn);
        l *= al;
#pragma unroll
        for (int w = 0; w < 8; ++w) acc[w] *= al;
        m = mn;
      }
      l += (p0 + p1) + (p2 + p3);
      const f32x4* vr0 = &Vs[(j + 0) * 8];
      const f32x4* vr1 = &Vs[(j + 1) * 8];
      const f32x4* vr2 = &Vs[(j + 2) * 8];
      const f32x4* vr3 = &Vs[(j + 3) * 8];
#pragma unroll
      for (int w = 0; w < 8; ++w)
        acc[w] += (p0 * vr0[w] + p1 * vr1[w]) + (p2 * vr2[w] + p3 * vr3[w]);
    }
  }
  float inv = 1.f / l;
  float* op = o + ((size_t)(b0 + bl) * 256 + tid) * DMODEL + hc;
#pragma unroll
  for (int w = 0; w < 8; ++w) *(f32x4*)(op + 4 * w) = acc[w] * inv;
}

// ---------------- query attention: block=batch, 256 thr=(head,row) ----------
__global__ __launch_bounds__(256) void k_attn_qry(const float* __restrict__ qkv,
    float* __restrict__ o) {
  __shared__ f32x4 Ks[32 * 64];
  __shared__ f32x4 Vs[32 * 64];
  int bl = blockIdx.x;
  int tid = threadIdx.x;
  const float* base = qkv + (size_t)bl * 32 * 768;
  for (int idx = tid; idx < 2048; idx += 256) {
    int s = idx >> 6, c = idx & 63;
    Ks[idx] = *(const f32x4*)(base + (size_t)s * 768 + 256 + c * 4);
    Vs[idx] = *(const f32x4*)(base + (size_t)s * 768 + 512 + c * 4);
  }
  __syncthreads();
  int h = tid >> 5, row = tid & 31;
  int hc = h * 32;
  f32x4 q[8], acc[8];
  const float* qp = base + (size_t)row * 768 + hc;
#pragma unroll
  for (int w = 0; w < 8; ++w) { q[w] = *(const f32x4*)(qp + 4 * w); acc[w] = 0.f; }
  float m = -1e30f, l = 0.f;
  const float scale = 0.17677669529663687f;
  for (int j = 0; j < 32; ++j) {
    const f32x4* kr = &Ks[j * 64 + h * 8];
    f32x4 da = q[0] * kr[0];
    f32x4 db = q[1] * kr[1];
#pragma unroll
    for (int w = 2; w < 8; w += 2) {
      da += q[w] * kr[w];
      db += q[w + 1] * kr[w + 1];
    }
    f32x4 d4 = da + db;
    float s_ = (d4[0] + d4[1] + d4[2] + d4[3]) * scale;
    float mn = fmaxf(m, s_);
    float p = __expf(s_ - mn);
    if (mn > m) {
      float al = __expf(m - mn);
      l *= al;
#pragma unroll
      for (int w = 0; w < 8; ++w) acc[w] *= al;
      m = mn;
    }
    l += p;
    const f32x4* vr = &Vs[j * 64 + h * 8];
#pragma unroll
    for (int w = 0; w < 8; ++w) acc[w] += p * vr[w];
  }
  float inv = 1.f / l;
  float* op = o + ((size_t)bl * 32 + row) * DMODEL + hc;
#pragma unroll
  for (int w = 0; w < 8; ++w) *(f32x4*)(op + 4 * w) = acc[w] * inv;
}

// ---------------- scoring stage 1 (R12-proven): block=(batch, query-half) ---
__global__ __launch_bounds__(256) void k_score(
    const int* __restrict__ qids, const int* __restrict__ dids,
    const float* __restrict__ emb, const float* __restrict__ xq,
    const float* __restrict__ xd, const float* __restrict__ a_ptr,
    const float* __restrict__ mlp_w, float* __restrict__ part) {
  __shared__ float qmix[16 * 256];
  __shared__ float qks[4][16][11];
  __shared__ float qmask_s[16];
  __shared__ float mw_s[11];
  int blk = blockIdx.x;
  int b = blk >> 1, half = blk & 1;
  int tid = threadIdx.x;
  int wv = tid >> 6, lane = tid & 63;
  float av = a_ptr[0], aw = 1.f - av;
  for (int q = 0; q < 16; ++q) {
    int qg = half * 16 + q;
    int qid = qids[b * 32 + qg];
    float qm = qid > 0 ? 1.f : 0.f;
    float ev = emb[(size_t)qid * 256 + tid];
    float xv = xq[((size_t)b * 32 + qg) * 256 + tid];
    qmix[q * 256 + tid] = (av * ev + aw * xv) * qm;
    if (tid == 0) qmask_s[q] = qm;
  }
  if (tid < 11) mw_s[tid] = mlp_w[tid];
  __syncthreads();
  int j = tid;
  int did = dids[b * 256 + j];
  float dmask = did > 0 ? 1.f : 0.f;
  float sim[16];
#pragma unroll
  for (int q = 0; q < 16; ++q) sim[q] = 0.f;
  const float4* de = (const float4*)(emb + (size_t)did * 256);
  const float4* dxp = (const float4*)(xd + ((size_t)b * 256 + j) * 256);
  for (int c = 0; c < 4; ++c) {
    float4 dreg[16];
#pragma unroll
    for (int w = 0; w < 16; ++w) {
      float4 e = de[c * 16 + w], x = dxp[c * 16 + w];
      dreg[w].x = av * e.x + aw * x.x;
      dreg[w].y = av * e.y + aw * x.y;
      dreg[w].z = av * e.z + aw * x.z;
      dreg[w].w = av * e.w + aw * x.w;
    }
#pragma unroll
    for (int q = 0; q < 16; ++q) {
      const float4* qp = (const float4*)&qmix[q * 256 + c * 64];
      float d_ = 0.f;
#pragma unroll
      for (int w = 0; w < 16; ++w) {
        float4 t = qp[w];
        d_ += t.x * dreg[w].x + t.y * dreg[w].y + t.z * dreg[w].z + t.w * dreg[w].w;
      }
      sim[q] += d_;
    }
  }
  const float MU[11] = {1.f, 0.9f, 0.7f, 0.5f, 0.3f, 0.1f, -0.1f, -0.3f, -0.5f, -0.7f, -0.9f};
  const float IC[11] = {5e7f, 50.f, 50.f, 50.f, 50.f, 50.f, 50.f, 50.f, 50.f, 50.f, 50.f};
  for (int q = 0; q < 16; ++q) {
    float s = sim[q];
    float f = dmask * qmask_s[q];
#pragma unroll
    for (int k = 0; k < 11; ++k) {
      float d_ = s - MU[k];
      float v = expf(-d_ * d_ * IC[k]) * f;
#pragma unroll
      for (int o = 32; o > 0; o >>= 1) v += __shfl_xor(v, o);
      if (lane == 0) qks[wv][q][k] = v;
    }
  }
  __syncthreads();
  if (tid < 176) {
    int q = tid / 11, k = tid - q * 11;
    float kv = (qks[0][q][k] + qks[1][q][k]) + (qks[2][q][k] + qks[3][q][k]);
    qks[0][q][k] = mw_s[k] * (qmask_s[q] * logf(fmaxf(kv, 1e-10f))
                              + kv * (1.f / 256.f));
  }
  __syncthreads();
  if (tid < 16) {
    float p = 0.f;
#pragma unroll
    for (int k = 0; k < 11; ++k) p += qks[0][tid][k];
#pragma unroll
    for (int o = 8; o > 0; o >>= 1) p += __shfl_xor(p, o);
    if (tid == 0) part[blk] = p;
  }
}

// ---------------- scoring stage 2: combine half partials --------------------
__global__ __launch_bounds__(256) void k_score_fin(const float* __restrict__ part,
    float* __restrict__ out) {
  int b = threadIdx.x;
  out[b] = part[2 * b] + part[2 * b + 1];
}

extern "C" void kernel_launch(void* const* d_in, const int* in_sizes, int n_in,
                              void* d_out, int out_size, void* d_ws, size_t ws_size,
                              hipStream_t stream) {
  const int* qids = (const int*)d_in[0];
  const int* dids = (const int*)d_in[1];
  const float* emb = (const float*)d_in[2];
  const float* a = (const float*)d_in[3];
  const float* mlp_w = (const float*)d_in[4];
  const float* Wqkv = (const float*)d_in[5];
  const float* bqkv = (const float*)d_in[6];
  const float* Wo = (const float*)d_in[7];
  const float* bo = (const float*)d_in[8];
  const float* l1s = (const float*)d_in[9];
  const float* l1b = (const float*)d_in[10];
  const float* W1 = (const float*)d_in[11];
  const float* b1 = (const float*)d_in[12];
  const float* W2 = (const float*)d_in[13];
  const float* b2 = (const float*)d_in[14];
  const float* l2s = (const float*)d_in[15];
  const float* l2b = (const float*)d_in[16];
  float* out = (float*)d_out;
  float* ws = (float*)d_ws;

  const int TOK = 73728;                      // 65536 doc + 8192 query tokens
  size_t wsf = ws_size / 4;
  const size_t fixed = 2 * (size_t)TOK * 256 + 65536;  // x + t0 + pe

  int FW = 128, CB = 32;
  bool merged = false;
  if (fixed + (size_t)40960 * 768 <= wsf) {
    merged = true; FW = 256; CB = 128;                                     // 277MB
  } else if (fixed + (size_t)128 * 196608 <= wsf) {
    FW = 256; CB = 128;                                                    // 252MB
  } else if (fixed + (size_t)TOK * 256 <= wsf) {
    FW = 256; CB = 64;                                                     // 227MB
  } else {
    FW = 128; CB = 32;                                                     // 189MB
  }

  float* x       = ws;
  float* t0      = x + (size_t)TOK * 256;
  float* pe      = t0 + (size_t)TOK * 256;
  float* scratch = pe + 65536;   // qkv chunk | h_part | score partials

  k_pe<<<256, 256, 0, stream>>>(pe);
  k_embed<<<TOK / 4, 256, 0, stream>>>(dids, qids, emb, pe, x);

  for (int l = 0; l < 2; ++l) {
    const float* wq = Wqkv + (size_t)l * 768 * 256;
    const float* bq = bqkv + l * 768;
    const float* wo = Wo + (size_t)l * 256 * 256;
    const float* bo_ = bo + l * 256;
    const float* w1 = W1 + (size_t)l * 2048 * 256;
    const float* b1_ = b1 + l * 2048;
    const float* w2 = W2 + (size_t)l * 256 * 2048;
    const float* b2_ = b2 + l * 256;

    if (merged) {
      k_gemm<false, false><<<dim3(6, 256), 256, 0, stream>>>(
          x, wq, bq, scratch, 32768, 768, 256, 256);
      k_attn_doc<<<1024, 256, 0, stream>>>(scratch, t0, 0);
      k_gemm<false, false><<<dim3(6, 320), 256, 0, stream>>>(
          x + (size_t)32768 * 256, wq, bq, scratch, 40960, 768, 256, 256);
      k_attn_doc<<<1024, 256, 0, stream>>>(scratch, t0, 128);
      k_attn_qry<<<256, 256, 0, stream>>>(scratch + (size_t)32768 * 768,
                                          t0 + (size_t)65536 * 256);
    } else {
      for (int c = 0; c < 256; c += CB) {
        int Mc = CB * 256;
        k_gemm<false, false><<<dim3(6, Mc / 128), 256, 0, stream>>>(
            x + (size_t)c * 65536, wq, bq, scratch, Mc, 768, 256, 256);
        k_attn_doc<<<CB * 8, 256, 0, stream>>>(scratch, t0, c);
      }
      k_gemm<false, false><<<dim3(6, 64), 256, 0, stream>>>(
          x + (size_t)65536 * 256, wq, bq, scratch, 8192, 768, 256, 256);
      k_attn_qry<<<256, 256, 0, stream>>>(scratch, t0 + (size_t)65536 * 256);
    }
    // Wo + bias + residual + LN1, in-place into x
    k_gemm_ln<false><<<TOK / 64, 256, 0, stream>>>(t0, wo, bo_, x, t0,
        l1s + l * 256, l1b + l * 256, TOK, 256, 256);
    // FFN, ff-sliced (FW); last W2 slice fused with residual+LN2
    int nparts = 2048 / FW;
    for (int p = 0; p < nparts; ++p) {
      k_gemm<true, false><<<dim3(FW / 128, TOK / 128), 256, 0, stream>>>(
          x, w1 + (size_t)p * FW * 256, b1_ + p * FW, scratch, TOK, FW, 256, 256);
      if (p == 0)
        k_gemm<false, false><<<dim3(2, TOK / 128), 256, 0, stream>>>(
            scratch, w2, b2_, t0, TOK, 256, FW, 2048);
      else if (p < nparts - 1)
        k_gemm<false, true><<<dim3(2, TOK / 128), 256, 0, stream>>>(
            scratch, w2 + (size_t)p * FW, b2_, t0, TOK, 256, FW, 2048);
      else
        k_gemm_ln<true><<<TOK / 64, 256, 0, stream>>>(
            scratch, w2 + (size_t)p * FW, b2_, x, t0,
            l2s + l * 256, l2b + l * 256, TOK, FW, 2048);
    }
  }

  // scoring: 2 blocks per batch -> partials -> combine
  float* part = scratch;
  k_score<<<512, 256, 0, stream>>>(qids, dids, emb, x + (size_t)65536 * 256,
                                   x, a, mlp_w, part);
  k_score_fin<<<1, 256, 0, stream>>>(part, out);
}